// Round 1
// baseline (375.665 us; speedup 1.0000x reference)
//
#include <hip/hip_runtime.h>

#define N_NODES 50000
#define N_EDGES 800000
#define F1 64
#define F2 16

// ---------- degree / norm ----------
__global__ void k_init_deg(float* __restrict__ deg) {
    int i = blockIdx.x * blockDim.x + threadIdx.x;
    if (i < N_NODES) deg[i] = 1.0f;  // self-loop
}

__global__ void k_count_deg(const int* __restrict__ dst, float* __restrict__ deg) {
    int i = blockIdx.x * blockDim.x + threadIdx.x;
    if (i < N_EDGES) atomicAdd(&deg[dst[i]], 1.0f);
}

__global__ void k_rsqrt(float* __restrict__ deg) {
    int i = blockIdx.x * blockDim.x + threadIdx.x;
    if (i < N_NODES) deg[i] = rsqrtf(deg[i]);
}

// ---------- layer 1 GEMM: h0 = x @ W1 ; agg1 = dinv^2 * h0 (self-loop init) ----------
__global__ void k_gemm1(const float* __restrict__ x, const float* __restrict__ W1,
                        const float* __restrict__ dinv,
                        float* __restrict__ h0, float* __restrict__ agg1) {
    __shared__ float Ws[F1 * F1];   // 16 KB
    __shared__ float Xs[4 * F1];    // 4 rows staged
    int tid = threadIdx.x;          // 256
    int row_local = tid >> 6;       // one wave per row -> Xs reads broadcast
    int col = tid & 63;
    int row = blockIdx.x * 4 + row_local;

    for (int i = tid; i < F1 * F1; i += 256) Ws[i] = W1[i];
    Xs[tid] = x[blockIdx.x * 4 * F1 + tid];
    __syncthreads();

    const float* xr = &Xs[row_local * F1];
    float acc = 0.f;
#pragma unroll
    for (int k = 0; k < F1; ++k) acc += xr[k] * Ws[k * F1 + col];  // stride-1 across lanes: conflict-free

    h0[row * F1 + col] = acc;
    float di = dinv[row];
    agg1[row * F1 + col] = di * di * acc;
}

// ---------- layer 1 edge scatter: agg1[d] += norm * h0[s], 64 lanes/edge ----------
__global__ void k_scatter64(const int* __restrict__ src, const int* __restrict__ dst,
                            const float* __restrict__ dinv, const float* __restrict__ h0,
                            float* __restrict__ agg1) {
    int idx = blockIdx.x * blockDim.x + threadIdx.x;  // max 51.2M < 2^31
    int e = idx >> 6;
    int f = idx & 63;
    if (e < N_EDGES) {
        int s = src[e], d = dst[e];
        float nrm = dinv[s] * dinv[d];
        atomicAdd(&agg1[d * F1 + f], nrm * h0[s * F1 + f]);
    }
}

// ---------- layer 2 GEMM (relu+b1 fused on read): h1 = relu(agg1+b1) @ W2 ;
//            out = b2 + dinv^2 * h1 (self-loop + bias init) ----------
__global__ void k_gemm2(const float* __restrict__ agg1, const float* __restrict__ b1,
                        const float* __restrict__ W2, const float* __restrict__ b2,
                        const float* __restrict__ dinv,
                        float* __restrict__ h1, float* __restrict__ out) {
    __shared__ float Ws[F1 * F2];       // 4 KB
    __shared__ float As[16 * 65];       // 16 rows, padded +1 to break 4-way bank conflict
    int tid = threadIdx.x;              // 256
    int rl = tid >> 4;                  // 0..15
    int col = tid & 15;
    int row = blockIdx.x * 16 + rl;

    for (int i = tid; i < F1 * F2; i += 256) Ws[i] = W2[i];
    for (int i = tid; i < 16 * F1; i += 256) {
        int k = i & 63;
        float v = agg1[blockIdx.x * 16 * F1 + i] + b1[k];
        As[(i >> 6) * 65 + k] = v > 0.f ? v : 0.f;
    }
    __syncthreads();

    const float* ar = &As[rl * 65];
    float acc = 0.f;
#pragma unroll
    for (int k = 0; k < F1; ++k) acc += ar[k] * Ws[k * F2 + col];  // Ws read is 16-addr broadcast

    h1[row * F2 + col] = acc;
    float di = dinv[row];
    out[row * F2 + col] = b2[col] + di * di * acc;
}

// ---------- layer 2 edge scatter: out[d] += norm * h1[s], 16 lanes/edge ----------
__global__ void k_scatter16(const int* __restrict__ src, const int* __restrict__ dst,
                            const float* __restrict__ dinv, const float* __restrict__ h1,
                            float* __restrict__ out) {
    int idx = blockIdx.x * blockDim.x + threadIdx.x;  // 12.8M
    int e = idx >> 4;
    int f = idx & 15;
    if (e < N_EDGES) {
        int s = src[e], d = dst[e];
        atomicAdd(&out[d * F2 + f], dinv[s] * dinv[d] * h1[s * F2 + f]);
    }
}

extern "C" void kernel_launch(void* const* d_in, const int* in_sizes, int n_in,
                              void* d_out, int out_size, void* d_ws, size_t ws_size,
                              hipStream_t stream) {
    const float* x  = (const float*)d_in[0];          // [50000, 64]
    const int*   ei = (const int*)d_in[1];            // [2, 800000] row-major
    const float* W1 = (const float*)d_in[2];          // [64, 64]
    const float* b1 = (const float*)d_in[3];          // [64]
    const float* W2 = (const float*)d_in[4];          // [64, 16]
    const float* b2 = (const float*)d_in[5];          // [16]
    float* out = (float*)d_out;                       // [50000, 16]

    const int* src = ei;
    const int* dst = ei + N_EDGES;

    // workspace layout (floats): dinv | h0 | agg1 | h1  -> ~29 MB
    float* ws   = (float*)d_ws;
    float* dinv = ws;                  // 50000 (padded to 50048)
    float* h0   = ws + 50048;          // 3,200,000
    float* agg1 = h0 + 3200000;        // 3,200,000
    float* h1   = agg1 + 3200000;      // 800,000

    k_init_deg <<<(N_NODES + 255) / 256, 256, 0, stream>>>(dinv);
    k_count_deg<<<(N_EDGES + 255) / 256, 256, 0, stream>>>(dst, dinv);
    k_rsqrt    <<<(N_NODES + 255) / 256, 256, 0, stream>>>(dinv);

    k_gemm1    <<<N_NODES / 4, 256, 0, stream>>>(x, W1, dinv, h0, agg1);
    k_scatter64<<<(N_EDGES * 64) / 256, 256, 0, stream>>>(src, dst, dinv, h0, agg1);
    k_gemm2    <<<N_NODES / 16, 256, 0, stream>>>(agg1, b1, W2, b2, dinv, h1, out);
    k_scatter16<<<(N_EDGES * 16) / 256, 256, 0, stream>>>(src, dst, dinv, h1, out);
}

// Round 2
// 369.825 us; speedup vs baseline: 1.0158x; 1.0158x over previous
//
#include <hip/hip_runtime.h>

#define N_NODES 50000
#define N_EDGES 800000
#define F1 64
#define F2 16

// ---------------- CSR build ----------------
__global__ void k_zero(int* __restrict__ off) {
    int i = blockIdx.x * blockDim.x + threadIdx.x;
    if (i < N_NODES) off[i] = 0;
}

__global__ void k_count(const int* __restrict__ dst, int* __restrict__ off) {
    int i = blockIdx.x * blockDim.x + threadIdx.x;
    if (i < N_EDGES) atomicAdd(&off[dst[i]], 1);
}

__global__ void k_dinv(const int* __restrict__ off, float* __restrict__ dinv) {
    int i = blockIdx.x * blockDim.x + threadIdx.x;
    if (i < N_NODES) dinv[i] = rsqrtf(1.0f + (float)off[i]);  // +1 self-loop
}

// single-block exclusive scan of counts -> offsets (in place). 1024 thr x 49 chunk.
__global__ void k_scan(int* __restrict__ off) {
    const int T = 1024, CH = 49;  // 1024*49 = 50176 >= N_NODES
    __shared__ int part[T];
    int t = threadIdx.x;
    int base = t * CH;
    int sum = 0;
    for (int i = 0; i < CH; ++i) {
        int idx = base + i;
        if (idx < N_NODES) sum += off[idx];
    }
    part[t] = sum;
    __syncthreads();
    for (int s = 1; s < T; s <<= 1) {           // Hillis-Steele inclusive scan
        int v = (t >= s) ? part[t - s] : 0;
        __syncthreads();
        part[t] += v;
        __syncthreads();
    }
    int prefix = (t == 0) ? 0 : part[t - 1];
    for (int i = 0; i < CH; ++i) {
        int idx = base + i;
        if (idx < N_NODES) {
            int c = off[idx];
            off[idx] = prefix;
            prefix += c;
        }
    }
}

// fill bucket lists; off[d] advances to bucket END (used as boundaries later)
__global__ void k_fill(const int* __restrict__ src, const int* __restrict__ dst,
                       int* __restrict__ off, int* __restrict__ csr_src) {
    int e = blockIdx.x * blockDim.x + threadIdx.x;
    if (e < N_EDGES) {
        int pos = atomicAdd(&off[dst[e]], 1);
        csr_src[pos] = src[e];
    }
}

// ---------------- layer 1 GEMM: h0 = x @ W1 ----------------
__global__ void k_gemm1(const float* __restrict__ x, const float* __restrict__ W1,
                        float* __restrict__ h0) {
    __shared__ float Ws[F1 * F1];   // 16 KB
    __shared__ float Xs[4 * F1];
    int tid = threadIdx.x;          // 256
    int row_local = tid >> 6;       // one wave per row
    int col = tid & 63;
    int row = blockIdx.x * 4 + row_local;

    for (int i = tid; i < F1 * F1; i += 256) Ws[i] = W1[i];
    Xs[tid] = x[blockIdx.x * 4 * F1 + tid];
    __syncthreads();

    const float* xr = &Xs[row_local * F1];
    float acc = 0.f;
#pragma unroll
    for (int k = 0; k < F1; ++k) acc += xr[k] * Ws[k * F1 + col];
    h0[row * F1 + col] = acc;
}

// ---------------- layer 1 gather: agg1[d] = dd*(dd*h0[d] + sum dinv[s]*h0[s]) ----------------
__global__ void k_gather1(const int* __restrict__ off, const int* __restrict__ csr_src,
                          const float* __restrict__ dinv, const float* __restrict__ h0,
                          float* __restrict__ agg1) {
    int tid = threadIdx.x;                 // 256 = 4 waves
    int lane = tid & 63;
    int d = blockIdx.x * 4 + (tid >> 6);   // one wave per node
    int start = (d == 0) ? 0 : off[d - 1]; // off holds bucket ENDS post-fill
    int end = off[d];
    float dd = dinv[d];
    float acc = dd * h0[d * F1 + lane];    // self-loop (dd factored out)
    int i = start;
    for (; i + 1 < end; i += 2) {          // 2-edge unroll for load ILP
        int s0 = csr_src[i], s1 = csr_src[i + 1];
        float w0 = dinv[s0], w1 = dinv[s1];
        float v0 = h0[s0 * F1 + lane], v1 = h0[s1 * F1 + lane];
        acc += w0 * v0 + w1 * v1;
    }
    if (i < end) {
        int s = csr_src[i];
        acc += dinv[s] * h0[s * F1 + lane];
    }
    agg1[d * F1 + lane] = dd * acc;
}

// ---------------- layer 2 GEMM: h1 = relu(agg1 + b1) @ W2 ----------------
__global__ void k_gemm2(const float* __restrict__ agg1, const float* __restrict__ b1,
                        const float* __restrict__ W2, float* __restrict__ h1) {
    __shared__ float Ws[F1 * F2];       // 4 KB
    __shared__ float As[16 * 65];       // +1 pad breaks bank conflicts
    int tid = threadIdx.x;              // 256
    int rl = tid >> 4;
    int col = tid & 15;
    int row = blockIdx.x * 16 + rl;

    for (int i = tid; i < F1 * F2; i += 256) Ws[i] = W2[i];
    for (int i = tid; i < 16 * F1; i += 256) {
        int k = i & 63;
        float v = agg1[blockIdx.x * 16 * F1 + i] + b1[k];
        As[(i >> 6) * 65 + k] = v > 0.f ? v : 0.f;
    }
    __syncthreads();

    const float* ar = &As[rl * 65];
    float acc = 0.f;
#pragma unroll
    for (int k = 0; k < F1; ++k) acc += ar[k] * Ws[k * F2 + col];
    h1[row * F2 + col] = acc;
}

// ---------------- layer 2 gather: out = b2 + dd*(dd*h1[d] + sum dinv[s]*h1[s]) ----------------
__global__ void k_gather2(const int* __restrict__ off, const int* __restrict__ csr_src,
                          const float* __restrict__ dinv, const float* __restrict__ h1,
                          const float* __restrict__ b2, float* __restrict__ out) {
    int tid = threadIdx.x;                 // 256 = 4 waves, one node per wave
    int lane = tid & 63;
    int j = lane >> 4;                     // 4 edges in parallel
    int f = lane & 15;
    int d = blockIdx.x * 4 + (tid >> 6);
    int start = (d == 0) ? 0 : off[d - 1];
    int end = off[d];
    float acc = 0.f;
    for (int i = start + j; i < end; i += 4) {
        int s = csr_src[i];
        acc += dinv[s] * h1[s * F2 + f];
    }
    acc += __shfl_xor(acc, 16);            // reduce the 4 j-groups
    acc += __shfl_xor(acc, 32);
    if (j == 0) {
        float dd = dinv[d];
        out[d * F2 + f] = b2[f] + dd * (dd * h1[d * F2 + f] + acc);
    }
}

extern "C" void kernel_launch(void* const* d_in, const int* in_sizes, int n_in,
                              void* d_out, int out_size, void* d_ws, size_t ws_size,
                              hipStream_t stream) {
    const float* x  = (const float*)d_in[0];          // [50000, 64]
    const int*   ei = (const int*)d_in[1];            // [2, 800000]
    const float* W1 = (const float*)d_in[2];          // [64, 64]
    const float* b1 = (const float*)d_in[3];          // [64]
    const float* W2 = (const float*)d_in[4];          // [64, 16]
    const float* b2 = (const float*)d_in[5];          // [16]
    float* out = (float*)d_out;                       // [50000, 16]

    const int* src = ei;
    const int* dst = ei + N_EDGES;

    // ws layout (4B units): dinv | offsets | csr_src | h0 (h1 aliases) | agg1  = 29.2 MB
    float* dinv    = (float*)d_ws;              // 50048
    int*   off     = (int*)d_ws + 50048;        // 50048
    int*   csr_src = (int*)d_ws + 100096;       // 800000
    float* h0      = (float*)d_ws + 900096;     // 3,200,000
    float* agg1    = (float*)d_ws + 4100096;    // 3,200,000
    float* h1      = h0;                        // reuse: h0 dead after gather1

    k_zero  <<<(N_NODES + 255) / 256, 256, 0, stream>>>(off);
    k_count <<<(N_EDGES + 255) / 256, 256, 0, stream>>>(dst, off);
    k_dinv  <<<(N_NODES + 255) / 256, 256, 0, stream>>>(off, dinv);
    k_scan  <<<1, 1024, 0, stream>>>(off);
    k_fill  <<<(N_EDGES + 255) / 256, 256, 0, stream>>>(src, dst, off, csr_src);

    k_gemm1   <<<N_NODES / 4, 256, 0, stream>>>(x, W1, h0);
    k_gather1 <<<N_NODES / 4, 256, 0, stream>>>(off, csr_src, dinv, h0, agg1);
    k_gemm2   <<<N_NODES / 16, 256, 0, stream>>>(agg1, b1, W2, h1);
    k_gather2 <<<N_NODES / 4, 256, 0, stream>>>(off, csr_src, dinv, h1, b2, out);
}

// Round 3
// 280.683 us; speedup vs baseline: 1.3384x; 1.3176x over previous
//
#include <hip/hip_runtime.h>

#define N_NODES 50000
#define N_EDGES 800000
#define F1 64
#define F2 16
#define SCAN_NB 196  // ceil(50000/256)

// ---------------- CSR build ----------------
__global__ void k_zero(int* __restrict__ off) {
    int i = blockIdx.x * blockDim.x + threadIdx.x;
    if (i < N_NODES) off[i] = 0;
}

__global__ void k_count(const int* __restrict__ dst, int* __restrict__ off) {
    int i = blockIdx.x * blockDim.x + threadIdx.x;
    if (i < N_EDGES) atomicAdd(&off[dst[i]], 1);
}

__global__ void k_dinv(const int* __restrict__ off, float* __restrict__ dinv) {
    int i = blockIdx.x * blockDim.x + threadIdx.x;
    if (i < N_NODES) dinv[i] = rsqrtf(1.0f + (float)off[i]);  // +1 self-loop
}

// hierarchical exclusive scan, step 1: per-block scan + block sums
__global__ void k_scan_local(int* __restrict__ off, int* __restrict__ bsum) {
    __shared__ int tmp[256];
    int t = threadIdx.x;
    int g = blockIdx.x * 256 + t;
    int v = (g < N_NODES) ? off[g] : 0;
    tmp[t] = v;
    __syncthreads();
    for (int s = 1; s < 256; s <<= 1) {   // Hillis-Steele inclusive
        int u = (t >= s) ? tmp[t - s] : 0;
        __syncthreads();
        tmp[t] += u;
        __syncthreads();
    }
    if (g < N_NODES) off[g] = tmp[t] - v; // exclusive
    if (t == 255) bsum[blockIdx.x] = tmp[255];
}

// step 2: exclusive scan of the 196 block sums (single tiny block)
__global__ void k_scan_sums(int* __restrict__ bsum) {
    __shared__ int tmp[256];
    int t = threadIdx.x;
    int v = (t < SCAN_NB) ? bsum[t] : 0;
    tmp[t] = v;
    __syncthreads();
    for (int s = 1; s < 256; s <<= 1) {
        int u = (t >= s) ? tmp[t - s] : 0;
        __syncthreads();
        tmp[t] += u;
        __syncthreads();
    }
    if (t < SCAN_NB) bsum[t] = tmp[t] - v;
}

// step 3: add block prefix
__global__ void k_scan_add(int* __restrict__ off, const int* __restrict__ bsum) {
    int g = blockIdx.x * 256 + threadIdx.x;
    if (g < N_NODES) off[g] += bsum[blockIdx.x];
}

// fill bucket lists; off[d] advances to bucket END (used as boundaries later)
__global__ void k_fill(const int* __restrict__ src, const int* __restrict__ dst,
                       int* __restrict__ off, int* __restrict__ csr_src) {
    int e = blockIdx.x * blockDim.x + threadIdx.x;
    if (e < N_EDGES) {
        int pos = atomicAdd(&off[dst[e]], 1);
        csr_src[pos] = src[e];
    }
}

// ---------------- layer 1 GEMM: h0 = x @ W1 ----------------
__global__ void k_gemm1(const float* __restrict__ x, const float* __restrict__ W1,
                        float* __restrict__ h0) {
    __shared__ float Ws[F1 * F1];   // 16 KB
    __shared__ float Xs[4 * F1];
    int tid = threadIdx.x;          // 256
    int row_local = tid >> 6;       // one wave per row
    int col = tid & 63;
    int row = blockIdx.x * 4 + row_local;

    for (int i = tid; i < F1 * F1; i += 256) Ws[i] = W1[i];
    Xs[tid] = x[blockIdx.x * 4 * F1 + tid];
    __syncthreads();

    const float* xr = &Xs[row_local * F1];
    float acc = 0.f;
#pragma unroll
    for (int k = 0; k < F1; ++k) acc += xr[k] * Ws[k * F1 + col];
    h0[row * F1 + col] = acc;
}

// ---------------- layer 1 gather: agg1[d] = dd*(dd*h0[d] + sum dinv[s]*h0[s]) ----------------
__global__ void k_gather1(const int* __restrict__ off, const int* __restrict__ csr_src,
                          const float* __restrict__ dinv, const float* __restrict__ h0,
                          float* __restrict__ agg1) {
    int tid = threadIdx.x;                 // 256 = 4 waves
    int lane = tid & 63;
    int d = blockIdx.x * 4 + (tid >> 6);   // one wave per node
    int start = (d == 0) ? 0 : off[d - 1]; // off holds bucket ENDS post-fill
    int end = off[d];
    float dd = dinv[d];
    float acc = dd * h0[d * F1 + lane];    // self-loop (dd factored out)
    int i = start;
    for (; i + 1 < end; i += 2) {          // 2-edge unroll for load ILP
        int s0 = csr_src[i], s1 = csr_src[i + 1];
        float w0 = dinv[s0], w1 = dinv[s1];
        float v0 = h0[s0 * F1 + lane], v1 = h0[s1 * F1 + lane];
        acc += w0 * v0 + w1 * v1;
    }
    if (i < end) {
        int s = csr_src[i];
        acc += dinv[s] * h0[s * F1 + lane];
    }
    agg1[d * F1 + lane] = dd * acc;
}

// ---------------- layer 2 GEMM: h1 = relu(agg1 + b1) @ W2 ----------------
__global__ void k_gemm2(const float* __restrict__ agg1, const float* __restrict__ b1,
                        const float* __restrict__ W2, float* __restrict__ h1) {
    __shared__ float Ws[F1 * F2];       // 4 KB
    __shared__ float As[16 * 65];       // +1 pad breaks bank conflicts
    int tid = threadIdx.x;              // 256
    int rl = tid >> 4;
    int col = tid & 15;
    int row = blockIdx.x * 16 + rl;

    for (int i = tid; i < F1 * F2; i += 256) Ws[i] = W2[i];
    for (int i = tid; i < 16 * F1; i += 256) {
        int k = i & 63;
        float v = agg1[blockIdx.x * 16 * F1 + i] + b1[k];
        As[(i >> 6) * 65 + k] = v > 0.f ? v : 0.f;
    }
    __syncthreads();

    const float* ar = &As[rl * 65];
    float acc = 0.f;
#pragma unroll
    for (int k = 0; k < F1; ++k) acc += ar[k] * Ws[k * F2 + col];
    h1[row * F2 + col] = acc;
}

// ---------------- layer 2 gather: out = b2 + dd*(dd*h1[d] + sum dinv[s]*h1[s]) ----------------
__global__ void k_gather2(const int* __restrict__ off, const int* __restrict__ csr_src,
                          const float* __restrict__ dinv, const float* __restrict__ h1,
                          const float* __restrict__ b2, float* __restrict__ out) {
    int tid = threadIdx.x;                 // 256 = 4 waves, one node per wave
    int lane = tid & 63;
    int j = lane >> 4;                     // 4 edges in parallel
    int f = lane & 15;
    int d = blockIdx.x * 4 + (tid >> 6);
    int start = (d == 0) ? 0 : off[d - 1];
    int end = off[d];
    float acc = 0.f;
    for (int i = start + j; i < end; i += 4) {
        int s = csr_src[i];
        acc += dinv[s] * h1[s * F2 + f];
    }
    acc += __shfl_xor(acc, 16);            // reduce the 4 j-groups
    acc += __shfl_xor(acc, 32);
    if (j == 0) {
        float dd = dinv[d];
        out[d * F2 + f] = b2[f] + dd * (dd * h1[d * F2 + f] + acc);
    }
}

extern "C" void kernel_launch(void* const* d_in, const int* in_sizes, int n_in,
                              void* d_out, int out_size, void* d_ws, size_t ws_size,
                              hipStream_t stream) {
    const float* x  = (const float*)d_in[0];          // [50000, 64]
    const int*   ei = (const int*)d_in[1];            // [2, 800000]
    const float* W1 = (const float*)d_in[2];          // [64, 64]
    const float* b1 = (const float*)d_in[3];          // [64]
    const float* W2 = (const float*)d_in[4];          // [64, 16]
    const float* b2 = (const float*)d_in[5];          // [16]
    float* out = (float*)d_out;                       // [50000, 16]

    const int* src = ei;
    const int* dst = ei + N_EDGES;

    // ws layout (4B units): dinv | offsets | csr_src | h0 (h1 aliases) | agg1 = 29.2 MB
    float* dinv    = (float*)d_ws;              // 50048
    int*   off     = (int*)d_ws + 50048;        // 50048
    int*   csr_src = (int*)d_ws + 100096;       // 800000
    float* h0      = (float*)d_ws + 900096;     // 3,200,000
    float* agg1    = (float*)d_ws + 4100096;    // 3,200,000
    float* h1      = h0;                        // reuse: h0 dead after gather1
    int*   bsum    = csr_src;                   // csr_src region dead until k_fill; bsum dead by then

    k_zero      <<<(N_NODES + 255) / 256, 256, 0, stream>>>(off);
    k_count     <<<(N_EDGES + 255) / 256, 256, 0, stream>>>(dst, off);
    k_dinv      <<<(N_NODES + 255) / 256, 256, 0, stream>>>(off, dinv);
    k_scan_local<<<SCAN_NB, 256, 0, stream>>>(off, bsum);
    k_scan_sums <<<1, 256, 0, stream>>>(bsum);
    k_scan_add  <<<SCAN_NB, 256, 0, stream>>>(off, bsum);
    k_fill      <<<(N_EDGES + 255) / 256, 256, 0, stream>>>(src, dst, off, csr_src);

    k_gemm1   <<<N_NODES / 4, 256, 0, stream>>>(x, W1, h0);
    k_gather1 <<<N_NODES / 4, 256, 0, stream>>>(off, csr_src, dinv, h0, agg1);
    k_gemm2   <<<N_NODES / 16, 256, 0, stream>>>(agg1, b1, W2, h1);
    k_gather2 <<<N_NODES / 4, 256, 0, stream>>>(off, csr_src, dinv, h1, b2, out);
}